// Round 5
// baseline (786.042 us; speedup 1.0000x reference)
//
#include <hip/hip_runtime.h>
#include <hip/hip_bf16.h>

#define B_ 16
#define S_ 2048
#define E_ 1024
#define M_ (B_ * S_)  // 32768

typedef unsigned short u16;
typedef float f32x4 __attribute__((ext_vector_type(4)));
typedef short s16x8 __attribute__((ext_vector_type(8)));
typedef unsigned short u16x8 __attribute__((ext_vector_type(8)));

__device__ __forceinline__ u16 f2bf(float f) {
    __hip_bfloat16 h = __float2bfloat16(f);
    return *reinterpret_cast<u16*>(&h);
}

__device__ __forceinline__ float bf2f(u16 v) {
    unsigned u = ((unsigned)v) << 16;
    return __uint_as_float(u);
}

__device__ __forceinline__ void gload_lds16(const void* g, void* lds) {
    __builtin_amdgcn_global_load_lds(
        (const __attribute__((address_space(1))) void*)g,
        (__attribute__((address_space(3))) void*)lds, 16, 0, 0);
}

// ---------------- fp32 -> bf16 conversion ----------------
__global__ __launch_bounds__(256) void cvt_f32_bf16(const float* __restrict__ src,
                                                    u16* __restrict__ dst, int n8) {
    for (int i = blockIdx.x * 256 + threadIdx.x; i < n8; i += gridDim.x * 256) {
        const float4* sp = (const float4*)src + (size_t)i * 2;
        float4 a = sp[0], b = sp[1];
        u16x8 o;
        o[0] = f2bf(a.x); o[1] = f2bf(a.y); o[2] = f2bf(a.z); o[3] = f2bf(a.w);
        o[4] = f2bf(b.x); o[5] = f2bf(b.y); o[6] = f2bf(b.z); o[7] = f2bf(b.w);
        *((u16x8*)dst + i) = o;
    }
}

// ---------------- V transpose: vt[b][d][s] = V[b][s][d] ----------------
__global__ __launch_bounds__(256) void transpose_v(const u16* __restrict__ V,
                                                   u16* __restrict__ vt) {
    int bid = blockIdx.x;  // 16 * 32 * 16
    int b = bid >> 9;
    int rem = bid & 511;
    int jt = rem >> 4, dt = rem & 15;
    __shared__ u16 lds[64 * 65];
    int t = threadIdx.x;
#pragma unroll
    for (int p = 0; p < 2; ++p) {
        int e = p * 2048 + t * 8;
        int j = e >> 6, d0 = e & 63;
        u16x8 v = *(const u16x8*)&V[((size_t)b * S_ + jt * 64 + j) * E_ + dt * 64 + d0];
#pragma unroll
        for (int q = 0; q < 8; ++q) lds[j * 65 + d0 + q] = v[q];
    }
    __syncthreads();
#pragma unroll
    for (int p = 0; p < 2; ++p) {
        int e = p * 2048 + t * 8;
        int d = e >> 6, j0 = e & 63;
        u16x8 o;
#pragma unroll
        for (int q = 0; q < 8; ++q) o[q] = lds[(j0 + q) * 65 + d];
        *(u16x8*)&vt[((size_t)b * E_ + dt * 64 + d) * S_ + jt * 64 + j0] = o;
    }
}

__device__ __forceinline__ int xcd_swizzle(int bid, int nwg) {
    int cpx = nwg >> 3;  // all grids divisible by 8
    return (bid & 7) * cpx + (bid >> 3);
}

// =============== 256x256 GEMM core, 8-phase m201 schedule, depth-3 ledger ===============
// C = A * B^T, A:[M][KLEN] bf16 row-major, B:[N][KLEN] bf16 row-major.
// 512 threads = 8 waves (2Mx4N), per-wave 128x64 out, acc[8][4] f32x4.
// LDS 128KB: buf{0,1} x {A:32KB, B:32KB}. BK=64.
// Swizzle: LDS linear (row,x) holds logical (row, x ^ ((row&7)<<4)) via
// pre-swizzled global src (gload dest linear) + swizzled ds_read (R4 scheme).
//
// Halves aligned with per-wave READ phases:
//   A-h0 = rows 0-63 & 128-191 (read at P0 by all waves), A-h1 = rest (P2).
//   B-h0 = 32-col stripes (c&63)<32 (read P0), B-h1 = rest (P1).
// 4 dual-barrier phases/K-tile, quadrants (0,0),(0,1),(1,0),(1,1), 16 MFMA each.
// Stage ledger (depth 3-4 phases between issue and wait):
//   P0: A-h0(kt+1); P1: A-h1(kt+1); P2: B-h0(kt+2); P3: B-h1(kt+2).
// Waits: end-P1 vmcnt(8) retires A-h1(kt) [needed P2]; end-P3 vmcnt(6)
// retires A-h0(kt+1) [needed next P0]. Edges: kt==KT-1 -> vmcnt(0) at P1;
// kt==KT-2 -> vmcnt(2) at P3. Prologue: tile0 all + B(1), vmcnt(4).
template <int KLEN>
__device__ __forceinline__ void gemm256_core(const u16* __restrict__ Abase,
                                             const u16* __restrict__ Bbase,
                                             char* lds, f32x4 acc[8][4], int tid) {
    constexpr int KT = KLEN / 64;
    const int w = tid >> 6, lane = tid & 63;
    const int wr = w >> 2, wc = w & 3;
    const int lrow = lane & 15;
    const int srow = lane >> 3;                  // 0..7
    const int scolb = ((lane & 7) ^ srow) << 4;  // pre-swizzled src col-bytes
    const int rsel = (lane >> 4) << 4;           // 16B sub-chunk within ksub
    const int rxor = (lane & 7) << 4;            // read-side swizzle

    auto stageA = [&](int kt, int h) {
        if (kt >= KT) return;
        char* reg = lds + ((kt & 1) ? 65536 : 0);
#pragma unroll
        for (int l = 0; l < 2; ++l) {
            const int row0 = h * 64 + l * 128 + w * 8;
            gload_lds16((const char*)Abase + (size_t)(row0 + srow) * (KLEN * 2) +
                            kt * 128 + scolb,
                        reg + row0 * 128);
        }
    };
    auto stageB = [&](int kt, int h) {
        if (kt >= KT) return;
        char* reg = lds + ((kt & 1) ? 65536 : 0) + 32768;
#pragma unroll
        for (int l = 0; l < 2; ++l) {
            const int row0 = l * 128 + (w >> 2) * 64 + h * 32 + (w & 3) * 8;
            gload_lds16((const char*)Bbase + (size_t)(row0 + srow) * (KLEN * 2) +
                            kt * 128 + scolb,
                        reg + row0 * 128);
        }
    };

    // prologue: tile0 (8 loads) + B halves of tile1 (4 loads); retire tile0
    stageA(0, 0); stageA(0, 1); stageB(0, 0); stageB(0, 1);
    stageB(1, 0); stageB(1, 1);
    asm volatile("s_waitcnt vmcnt(4)" ::: "memory");
    __builtin_amdgcn_s_barrier();
    __builtin_amdgcn_sched_barrier(0);

    s16x8 a[4][2], b0[2][2], b1[2][2];
#pragma unroll 1
    for (int kt = 0; kt < KT; ++kt) {
        const char* sA = lds + ((kt & 1) ? 65536 : 0);
        const char* sB = sA + 32768;
        // ---- P0: read A-h0(8) + B-h0(4); stage A-h0(kt+1); MFMA Q(0,0)
#pragma unroll
        for (int mi = 0; mi < 4; ++mi) {
            const int r = wr * 128 + mi * 16 + lrow;
#pragma unroll
            for (int ks = 0; ks < 2; ++ks)
                a[mi][ks] = *(const s16x8*)(sA + r * 128 + ((ks * 64 + rsel) ^ rxor));
        }
#pragma unroll
        for (int ni = 0; ni < 2; ++ni) {
            const int c = wc * 64 + ni * 16 + lrow;
#pragma unroll
            for (int ks = 0; ks < 2; ++ks)
                b0[ni][ks] = *(const s16x8*)(sB + c * 128 + ((ks * 64 + rsel) ^ rxor));
        }
        stageA(kt + 1, 0);
        asm volatile("s_waitcnt lgkmcnt(8)" ::: "memory");
        __builtin_amdgcn_s_barrier();
        asm volatile("s_waitcnt lgkmcnt(0)" ::: "memory");
        __builtin_amdgcn_sched_barrier(0);
        __builtin_amdgcn_s_setprio(1);
#pragma unroll
        for (int mi = 0; mi < 4; ++mi)
#pragma unroll
            for (int ni = 0; ni < 2; ++ni)
#pragma unroll
                for (int ks = 0; ks < 2; ++ks)
                    acc[mi][ni] = __builtin_amdgcn_mfma_f32_16x16x32_bf16(
                        a[mi][ks], b0[ni][ks], acc[mi][ni], 0, 0, 0);
        __builtin_amdgcn_s_setprio(0);
        __builtin_amdgcn_sched_barrier(0);
        __builtin_amdgcn_s_barrier();
        // ---- P1: read B-h1(4); stage A-h1(kt+1); MFMA Q(0,1); vmcnt(8|0)
#pragma unroll
        for (int ni = 0; ni < 2; ++ni) {
            const int c = wc * 64 + 32 + ni * 16 + lrow;
#pragma unroll
            for (int ks = 0; ks < 2; ++ks)
                b1[ni][ks] = *(const s16x8*)(sB + c * 128 + ((ks * 64 + rsel) ^ rxor));
        }
        stageA(kt + 1, 1);
        __builtin_amdgcn_s_barrier();
        asm volatile("s_waitcnt lgkmcnt(0)" ::: "memory");
        __builtin_amdgcn_sched_barrier(0);
        __builtin_amdgcn_s_setprio(1);
#pragma unroll
        for (int mi = 0; mi < 4; ++mi)
#pragma unroll
            for (int ni = 0; ni < 2; ++ni)
#pragma unroll
                for (int ks = 0; ks < 2; ++ks)
                    acc[mi][2 + ni] = __builtin_amdgcn_mfma_f32_16x16x32_bf16(
                        a[mi][ks], b1[ni][ks], acc[mi][2 + ni], 0, 0, 0);
        __builtin_amdgcn_s_setprio(0);
        __builtin_amdgcn_sched_barrier(0);
        if (kt == KT - 1) asm volatile("s_waitcnt vmcnt(0)" ::: "memory");
        else              asm volatile("s_waitcnt vmcnt(8)" ::: "memory");
        __builtin_amdgcn_s_barrier();
        // ---- P2: read A-h1(8); stage B-h0(kt+2); MFMA Q(1,0)
#pragma unroll
        for (int mi = 0; mi < 4; ++mi) {
            const int r = wr * 128 + 64 + mi * 16 + lrow;
#pragma unroll
            for (int ks = 0; ks < 2; ++ks)
                a[mi][ks] = *(const s16x8*)(sA + r * 128 + ((ks * 64 + rsel) ^ rxor));
        }
        stageB(kt + 2, 0);
        __builtin_amdgcn_s_barrier();
        asm volatile("s_waitcnt lgkmcnt(0)" ::: "memory");
        __builtin_amdgcn_sched_barrier(0);
        __builtin_amdgcn_s_setprio(1);
#pragma unroll
        for (int mi = 0; mi < 4; ++mi)
#pragma unroll
            for (int ni = 0; ni < 2; ++ni)
#pragma unroll
                for (int ks = 0; ks < 2; ++ks)
                    acc[4 + mi][ni] = __builtin_amdgcn_mfma_f32_16x16x32_bf16(
                        a[mi][ks], b0[ni][ks], acc[4 + mi][ni], 0, 0, 0);
        __builtin_amdgcn_s_setprio(0);
        __builtin_amdgcn_sched_barrier(0);
        __builtin_amdgcn_s_barrier();
        // ---- P3: no reads; stage B-h1(kt+2); MFMA Q(1,1); vmcnt(6|2)
        stageB(kt + 2, 1);
        __builtin_amdgcn_s_barrier();
        __builtin_amdgcn_sched_barrier(0);
        __builtin_amdgcn_s_setprio(1);
#pragma unroll
        for (int mi = 0; mi < 4; ++mi)
#pragma unroll
            for (int ni = 0; ni < 2; ++ni)
#pragma unroll
                for (int ks = 0; ks < 2; ++ks)
                    acc[4 + mi][2 + ni] = __builtin_amdgcn_mfma_f32_16x16x32_bf16(
                        a[mi][ks], b1[ni][ks], acc[4 + mi][2 + ni], 0, 0, 0);
        __builtin_amdgcn_s_setprio(0);
        __builtin_amdgcn_sched_barrier(0);
        if (kt == KT - 2) asm volatile("s_waitcnt vmcnt(2)" ::: "memory");
        else if (kt < KT - 2) asm volatile("s_waitcnt vmcnt(6)" ::: "memory");
        __builtin_amdgcn_s_barrier();
        __builtin_amdgcn_sched_barrier(0);
    }
}

// ---------------- QKV projection: [32768,3072] = xb @ Wb^T + bias -> bf16 ----------------
__global__ __launch_bounds__(512, 2) void gemm_qkv(const u16* __restrict__ xb,
                                                   const u16* __restrict__ Wb,
                                                   const float* __restrict__ bq,
                                                   const float* __restrict__ bk,
                                                   const float* __restrict__ bvp,
                                                   u16* __restrict__ qkv) {
    __shared__ f32x4 smem[8192];  // 128 KiB
    char* lds = (char*)smem;
    int wg = xcd_swizzle(blockIdx.x, 1536);
    int mt = wg / 12, nt = wg % 12;
    f32x4 acc[8][4];
    f32x4 zero = {0.f, 0.f, 0.f, 0.f};
#pragma unroll
    for (int i = 0; i < 8; ++i)
#pragma unroll
        for (int j = 0; j < 4; ++j) acc[i][j] = zero;
    gemm256_core<E_>(xb + (size_t)mt * 256 * E_, Wb + (size_t)nt * 256 * E_, lds, acc,
                     threadIdx.x);

    int tid = threadIdx.x, w = tid >> 6, lane = tid & 63, wr = w >> 2, wc = w & 3;
    int mat = nt >> 2;  // 4 n-tiles per matrix
    const float* bias = (mat == 0) ? bq : ((mat == 1) ? bk : bvp);
    u16* outm = qkv + (size_t)mat * M_ * E_;
    int bn = (nt & 3) * 256;
#pragma unroll
    for (int b = 0; b < 4; ++b) {
        int n = bn + wc * 64 + (b >> 1) * 32 + (b & 1) * 16 + (lane & 15);
        float bb = bias[n];
#pragma unroll
        for (int a = 0; a < 8; ++a)
#pragma unroll
            for (int j = 0; j < 4; ++j) {
                int m = mt * 256 + wr * 128 + (a >> 2) * 64 + (a & 3) * 16 +
                        ((lane >> 4) << 2) + j;
                outm[(size_t)m * E_ + n] = f2bf(acc[a][b][j] + bb);
            }
    }
}

// ---------------- scores+exp -> bf16 P, row-sum atomics ----------------
__global__ __launch_bounds__(512, 2) void gemm_sexp(const u16* __restrict__ qkv,
                                                    u16* __restrict__ Pbuf,
                                                    float* __restrict__ lsum, int b0) {
    __shared__ f32x4 smem[8192];
    char* lds = (char*)smem;
    int wg = xcd_swizzle(blockIdx.x, gridDim.x);
    int ci = wg >> 6, rem = wg & 63, mt = rem >> 3, ntt = rem & 7;
    int bb = b0 + ci;
    const u16* Q = qkv + ((size_t)bb * S_ + mt * 256) * E_;
    const u16* K = qkv + (size_t)M_ * E_ + ((size_t)bb * S_ + ntt * 256) * E_;
    f32x4 acc[8][4];
    f32x4 zero = {0.f, 0.f, 0.f, 0.f};
#pragma unroll
    for (int i = 0; i < 8; ++i)
#pragma unroll
        for (int j = 0; j < 4; ++j) acc[i][j] = zero;
    gemm256_core<E_>(Q, K, lds, acc, threadIdx.x);

    int tid = threadIdx.x, w = tid >> 6, lane = tid & 63, wr = w >> 2, wc = w & 3;
#pragma unroll
    for (int a = 0; a < 8; ++a)
#pragma unroll
        for (int j = 0; j < 4; ++j) {
            int m = mt * 256 + wr * 128 + (a >> 2) * 64 + (a & 3) * 16 + ((lane >> 4) << 2) + j;
            size_t base = ((size_t)ci * S_ + m) * S_;
            float psum = 0.f;
            u16 pb[4];
#pragma unroll
            for (int b = 0; b < 4; ++b) {
                float p = __expf(acc[a][b][j] * 0.03125f);
                pb[b] = f2bf(p);
                psum += bf2f(pb[b]);
            }
#pragma unroll
            for (int b = 0; b < 4; ++b) {
                int n = ntt * 256 + wc * 64 + (b >> 1) * 32 + (b & 1) * 16 + (lane & 15);
                Pbuf[base + n] = pb[b];
            }
            psum += __shfl_xor(psum, 1, 64);
            psum += __shfl_xor(psum, 2, 64);
            psum += __shfl_xor(psum, 4, 64);
            psum += __shfl_xor(psum, 8, 64);
            if ((lane & 15) == 0) atomicAdd(&lsum[(size_t)bb * S_ + m], psum);
        }
}

// ---------------- PV: out = (P @ vt^T) / lsum (fp32) ----------------
__global__ __launch_bounds__(512, 2) void gemm_pv(const u16* __restrict__ Pbuf,
                                                  const u16* __restrict__ vt,
                                                  const float* __restrict__ lsum,
                                                  float* __restrict__ out, int b0) {
    __shared__ f32x4 smem[8192];
    char* lds = (char*)smem;
    int wg = xcd_swizzle(blockIdx.x, gridDim.x);
    int ci = wg >> 5, rem = wg & 31, mt = rem >> 2, ntt = rem & 3;
    int bb = b0 + ci;
    const u16* A = Pbuf + (size_t)ci * S_ * S_ + (size_t)mt * 256 * S_;
    const u16* Bb = vt + ((size_t)bb * E_ + ntt * 256) * S_;
    f32x4 acc[8][4];
    f32x4 zero = {0.f, 0.f, 0.f, 0.f};
#pragma unroll
    for (int i = 0; i < 8; ++i)
#pragma unroll
        for (int j = 0; j < 4; ++j) acc[i][j] = zero;
    gemm256_core<S_>(A, Bb, lds, acc, threadIdx.x);

    int tid = threadIdx.x, w = tid >> 6, lane = tid & 63, wr = w >> 2, wc = w & 3;
#pragma unroll
    for (int a = 0; a < 8; ++a)
#pragma unroll
        for (int j = 0; j < 4; ++j) {
            int m = mt * 256 + wr * 128 + (a >> 2) * 64 + (a & 3) * 16 + ((lane >> 4) << 2) + j;
            float inv = 1.0f / lsum[(size_t)bb * S_ + m];
#pragma unroll
            for (int b = 0; b < 4; ++b) {
                int n = ntt * 256 + wc * 64 + (b >> 1) * 32 + (b & 1) * 16 + (lane & 15);
                out[((size_t)bb * S_ + m) * E_ + n] = acc[a][b][j] * inv;
            }
        }
}

extern "C" void kernel_launch(void* const* d_in, const int* in_sizes, int n_in,
                              void* d_out, int out_size, void* d_ws, size_t ws_size,
                              hipStream_t stream) {
    const float* x = (const float*)d_in[0];
    const float* Wq = (const float*)d_in[1];
    const float* bq = (const float*)d_in[2];
    const float* Wk = (const float*)d_in[3];
    const float* bk = (const float*)d_in[4];
    const float* Wv = (const float*)d_in[5];
    const float* bv = (const float*)d_in[6];
    float* out = (float*)d_out;

    char* ws = (char*)d_ws;
    const size_t xb_off = 0;
    const size_t wb_off = xb_off + (size_t)M_ * E_ * 2;       // 64 MiB
    const size_t qkv_off = wb_off + (size_t)3 * E_ * E_ * 2;  // +6 MiB
    const size_t vt_off = qkv_off + (size_t)3 * M_ * E_ * 2;  // +192 MiB
    const size_t l_off = vt_off + (size_t)M_ * E_ * 2;        // +64 MiB
    const size_t chunk_off = l_off + (size_t)M_ * 4;          // +128 KiB

    u16* xb = (u16*)(ws + xb_off);
    u16* Wb = (u16*)(ws + wb_off);
    u16* qkv = (u16*)(ws + qkv_off);
    u16* vt = (u16*)(ws + vt_off);
    float* lsum = (float*)(ws + l_off);

    int CH = 16;
    while (CH > 1 && chunk_off + (size_t)CH * S_ * S_ * 2 > ws_size) CH >>= 1;
    u16* Pbuf = (u16*)(ws + chunk_off);

    hipMemsetAsync(lsum, 0, (size_t)M_ * 4, stream);

    cvt_f32_bf16<<<2048, 256, 0, stream>>>(x, xb, M_ * E_ / 8);
    cvt_f32_bf16<<<512, 256, 0, stream>>>(Wq, Wb, E_ * E_ / 8);
    cvt_f32_bf16<<<512, 256, 0, stream>>>(Wk, Wb + E_ * E_, E_ * E_ / 8);
    cvt_f32_bf16<<<512, 256, 0, stream>>>(Wv, Wb + 2 * E_ * E_, E_ * E_ / 8);

    gemm_qkv<<<1536, 512, 0, stream>>>(xb, Wb, bq, bk, bv, qkv);
    transpose_v<<<16 * 32 * 16, 256, 0, stream>>>(qkv + (size_t)2 * M_ * E_, vt);

    for (int b0 = 0; b0 < B_; b0 += CH) {
        gemm_sexp<<<CH * 64, 512, 0, stream>>>(qkv, Pbuf, lsum, b0);
        gemm_pv<<<CH * 32, 512, 0, stream>>>(Pbuf, vt, lsum, out, b0);
    }
}